// Round 1
// baseline (574.676 us; speedup 1.0000x reference)
//
#include <hip/hip_runtime.h>
#include <math.h>

#define KW 7
#define DIL 2
#define PADW 12          // (KW-1)*DIL
#define BATCH 8
#define CIN 128
#define COUT 256
#define LEN 4096
#define L2V 4108         // LEN + PADW
#define NQKV 768

// ---------------------------------------------------------------------------
// Kernel 1: weight norm  w1[o,ci,t] = g[o] * v[o,ci,t] / ||v[o]||
// ---------------------------------------------------------------------------
__global__ __launch_bounds__(256) void wn_kernel(
    const float* __restrict__ v, const float* __restrict__ g,
    float* __restrict__ w1)
{
  const int o = blockIdx.x;
  const float* vo = v + (size_t)o * (CIN * KW);
  float s = 0.f;
  for (int i = threadIdx.x; i < CIN * KW; i += 256) { float t = vo[i]; s += t * t; }
#pragma unroll
  for (int off = 1; off < 64; off <<= 1) s += __shfl_xor(s, off);
  __shared__ float red[4];
  if ((threadIdx.x & 63) == 0) red[threadIdx.x >> 6] = s;
  __syncthreads();
  const float tot = red[0] + red[1] + red[2] + red[3];
  const float scale = g[o] / sqrtf(tot);
  for (int i = threadIdx.x; i < CIN * KW; i += 256)
    w1[(size_t)o * (CIN * KW) + i] = vo[i] * scale;
}

// ---------------------------------------------------------------------------
// Kernel 2: zero h[:, 0:PADW, :]  (left pad rows of h)
// ---------------------------------------------------------------------------
__global__ __launch_bounds__(256) void zero_hpad_kernel(float* __restrict__ h)
{
  const int i = blockIdx.x * 256 + threadIdx.x;     // < BATCH*PADW*COUT
  const int b = i / (PADW * COUT);
  const int rem = i - b * (PADW * COUT);
  h[(size_t)b * L2V * COUT + rem] = 0.f;
}

// ---------------------------------------------------------------------------
// Kernel 3: dilated conv + bias + relu -> h[b, p+PADW, c]
//   conv_out[b,c,p] = sum_{ci,t} x[b,ci,p+2t-12] * w1[c,ci,t],  p in [0,4096)
//   64 pos x 64 ch tile, 4x4 per thread, K-slab of 8 ci (56 (ci,t) pairs)
// ---------------------------------------------------------------------------
__global__ __launch_bounds__(256) void conv_kernel(
    const float* __restrict__ x, const float* __restrict__ w1,
    const float* __restrict__ bias, float* __restrict__ h)
{
  const int b  = blockIdx.z;
  const int c0 = blockIdx.y * 64;
  const int p0 = blockIdx.x * 64;
  const int tid = threadIdx.x;
  const int tx = tid & 15, ty = tid >> 4;

  __shared__ float xs[8][80];     // 8 ci x 76 positions (p0-12 .. p0+63)
  __shared__ float wsT[56][68];   // [ci*7+t][channel]

  float acc[4][4] = {};
  const float* xb = x + (size_t)b * CIN * LEN;

  for (int ci0 = 0; ci0 < CIN; ci0 += 8) {
    for (int idx = tid; idx < 8 * 76; idx += 256) {
      const int ci = idx / 76, off = idx - ci * 76;
      const int gidx = p0 - PADW + off;
      xs[ci][off] = (gidx >= 0 && gidx < LEN) ? xb[(size_t)(ci0 + ci) * LEN + gidx] : 0.f;
    }
    for (int idx = tid; idx < 64 * 56; idx += 256) {
      const int c = idx / 56, kk = idx - c * 56;
      const int ci = kk / 7, t = kk - ci * 7;
      wsT[kk][c] = w1[((size_t)(c0 + c) * CIN + (ci0 + ci)) * KW + t];
    }
    __syncthreads();
#pragma unroll
    for (int kk = 0; kk < 56; ++kk) {
      const int ci = kk / 7, t = kk - (kk / 7) * 7;
      const float4 a = *(const float4*)&wsT[kk][ty * 4];
      const float av[4] = {a.x, a.y, a.z, a.w};
      float bv[4];
#pragma unroll
      for (int j = 0; j < 4; ++j) bv[j] = xs[ci][tx * 4 + j + 2 * t];
#pragma unroll
      for (int i = 0; i < 4; ++i)
#pragma unroll
        for (int j = 0; j < 4; ++j) acc[i][j] += av[i] * bv[j];
    }
    __syncthreads();
  }

#pragma unroll
  for (int i = 0; i < 4; ++i) {
    const int c = c0 + ty * 4 + i;
    const float bb = bias[c];
#pragma unroll
    for (int j = 0; j < 4; ++j) {
      const int p = p0 + tx * 4 + j;
      float vv = acc[i][j] + bb;
      vv = vv > 0.f ? vv : 0.f;
      h[((size_t)b * L2V + (p + PADW)) * COUT + c] = vv;
    }
  }
}

// ---------------------------------------------------------------------------
// Kernel 4: C[m,n] = sum_k A[m,k]*Bw[n,k] + bias[n]   (A row-major MxK,
// Bw row-major NxK).  64x64 tile, 4x4/thread, K-slab 16.
// ---------------------------------------------------------------------------
__global__ __launch_bounds__(256) void gemm_bias_kernel(
    const float* __restrict__ A, const float* __restrict__ Bw,
    const float* __restrict__ bias, float* __restrict__ C,
    const int M, const int N, const int K)
{
  const int m0 = blockIdx.x * 64, n0 = blockIdx.y * 64;
  const int tid = threadIdx.x;
  const int tx = tid & 15, ty = tid >> 4;
  __shared__ float As[16][68], Bs[16][68];
  float acc[4][4] = {};
  const int idx = tid * 4;
  const int lm = idx >> 4, lk = idx & 15;   // lm: row 0..63, lk: 0/4/8/12

  for (int k0 = 0; k0 < K; k0 += 16) {
    float4 va = (m0 + lm < M) ? *(const float4*)(A + (size_t)(m0 + lm) * K + k0 + lk)
                              : make_float4(0.f, 0.f, 0.f, 0.f);
    As[lk + 0][lm] = va.x; As[lk + 1][lm] = va.y; As[lk + 2][lm] = va.z; As[lk + 3][lm] = va.w;
    float4 vb = (n0 + lm < N) ? *(const float4*)(Bw + (size_t)(n0 + lm) * K + k0 + lk)
                              : make_float4(0.f, 0.f, 0.f, 0.f);
    Bs[lk + 0][lm] = vb.x; Bs[lk + 1][lm] = vb.y; Bs[lk + 2][lm] = vb.z; Bs[lk + 3][lm] = vb.w;
    __syncthreads();
#pragma unroll
    for (int kk = 0; kk < 16; ++kk) {
      const float4 a  = *(const float4*)&As[kk][ty * 4];
      const float4 bb = *(const float4*)&Bs[kk][tx * 4];
      const float av[4] = {a.x, a.y, a.z, a.w};
      const float bv[4] = {bb.x, bb.y, bb.z, bb.w};
#pragma unroll
      for (int i = 0; i < 4; ++i)
#pragma unroll
        for (int j = 0; j < 4; ++j) acc[i][j] += av[i] * bv[j];
    }
    __syncthreads();
  }
#pragma unroll
  for (int i = 0; i < 4; ++i) {
    const int m = m0 + ty * 4 + i;
    if (m >= M) continue;
#pragma unroll
    for (int j = 0; j < 4; ++j) {
      const int n = n0 + tx * 4 + j;
      C[(size_t)m * N + n] = acc[i][j] + bias[n];
    }
  }
}

// ---------------------------------------------------------------------------
// Kernel 5: NATTEN 1D dilated attention, one wave per (b, j), j in [0,4096)
//   qkv layout: (B*L2V, 768) = [q | k | v]
//   ao: (B, 4096, 256)
// ---------------------------------------------------------------------------
__global__ __launch_bounds__(256) void attn_kernel(
    const float* __restrict__ qkv, const float* __restrict__ rpb,
    float* __restrict__ ao)
{
  const int wid  = (blockIdx.x << 2) + (threadIdx.x >> 6);  // 0..BATCH*LEN-1
  const int lane = threadIdx.x & 63;
  const int b = wid >> 12;
  const int j = wid & 4095;
  const int r = j & 1, ii = j >> 1;
  int start = ii - 3;
  start = start < 0 ? 0 : start;
  start = start > 2047 ? 2047 : start;   // Lg - KW = 2054 - 7

  const float* base = qkv + (size_t)b * L2V * NQKV;
  const float* qrow = base + (size_t)j * NQKV;
  const float q0 = qrow[lane]       * 0.0625f;
  const float q1 = qrow[64 + lane]  * 0.0625f;
  const float q2 = qrow[128 + lane] * 0.0625f;
  const float q3 = qrow[192 + lane] * 0.0625f;

  float sc[7];
  float mx = -1e30f;
#pragma unroll
  for (int t = 0; t < 7; ++t) {
    const int pos = r + 2 * (start + t);
    const float* krow = base + (size_t)pos * NQKV + COUT;
    float s = q0 * krow[lane] + q1 * krow[64 + lane] +
              q2 * krow[128 + lane] + q3 * krow[192 + lane];
#pragma unroll
    for (int o = 1; o < 64; o <<= 1) s += __shfl_xor(s, o);
    s += rpb[start + t - ii + 6];
    sc[t] = s;
    mx = fmaxf(mx, s);
  }
  float sum = 0.f;
#pragma unroll
  for (int t = 0; t < 7; ++t) { sc[t] = expf(sc[t] - mx); sum += sc[t]; }
  const float inv = 1.f / sum;

  float a0 = 0.f, a1 = 0.f, a2 = 0.f, a3 = 0.f;
#pragma unroll
  for (int t = 0; t < 7; ++t) {
    const int pos = r + 2 * (start + t);
    const float* vrow = base + (size_t)pos * NQKV + 2 * COUT;
    const float w = sc[t] * inv;
    a0 += w * vrow[lane];
    a1 += w * vrow[64 + lane];
    a2 += w * vrow[128 + lane];
    a3 += w * vrow[192 + lane];
  }
  float* aor = ao + ((size_t)(b * LEN + j)) * COUT;
  aor[lane] = a0; aor[64 + lane] = a1; aor[128 + lane] = a2; aor[192 + lane] = a3;
}

// ---------------------------------------------------------------------------
// Kernel 6: out[b,o,l] = relu( relu(proj(ao)[b,l,o]+pb[o]) + ds(x)[b,o,l]+db[o] )
// ---------------------------------------------------------------------------
__global__ __launch_bounds__(256) void proj_res_kernel(
    const float* __restrict__ ao, const float* __restrict__ pw,
    const float* __restrict__ pb, const float* __restrict__ x,
    const float* __restrict__ dw, const float* __restrict__ db,
    float* __restrict__ out)
{
  const int b  = blockIdx.z;
  const int l0 = blockIdx.x * 64, o0 = blockIdx.y * 64;
  const int tid = threadIdx.x;
  const int tx = tid & 15, ty = tid >> 4;
  __shared__ float As[16][68], Bs[16][68];
  const int idx = tid * 4;

  // ---- phase 1: proj GEMM over c=0..255 ----
  float acc[4][4] = {};   // [o][l]
  const float* aob = ao + (size_t)b * LEN * COUT;
  {
    const int lm = idx >> 4, lk = idx & 15;
    for (int k0 = 0; k0 < COUT; k0 += 16) {
      float4 va = *(const float4*)(aob + (size_t)(l0 + lm) * COUT + k0 + lk);
      As[lk + 0][lm] = va.x; As[lk + 1][lm] = va.y; As[lk + 2][lm] = va.z; As[lk + 3][lm] = va.w;
      float4 vb = *(const float4*)(pw + (size_t)(o0 + lm) * COUT + k0 + lk);
      Bs[lk + 0][lm] = vb.x; Bs[lk + 1][lm] = vb.y; Bs[lk + 2][lm] = vb.z; Bs[lk + 3][lm] = vb.w;
      __syncthreads();
#pragma unroll
      for (int kk = 0; kk < 16; ++kk) {
        const float4 a  = *(const float4*)&Bs[kk][ty * 4];   // o
        const float4 bb = *(const float4*)&As[kk][tx * 4];   // l
        const float av[4] = {a.x, a.y, a.z, a.w};
        const float bv[4] = {bb.x, bb.y, bb.z, bb.w};
#pragma unroll
        for (int i = 0; i < 4; ++i)
#pragma unroll
          for (int j = 0; j < 4; ++j) acc[i][j] += av[i] * bv[j];
      }
      __syncthreads();
    }
  }
  float r1[4][4];
#pragma unroll
  for (int i = 0; i < 4; ++i) {
    const float pbv = pb[o0 + ty * 4 + i];
#pragma unroll
    for (int j = 0; j < 4; ++j) {
      float vv = acc[i][j] + pbv;
      r1[i][j] = vv > 0.f ? vv : 0.f;
    }
  }

  // ---- phase 2: ds residual GEMM over ci=0..127 ----
  float acc2[4][4] = {};
  const float* xb = x + (size_t)b * CIN * LEN;
  {
    const int xk = idx >> 6, xl = idx & 63;   // Xs stage: 16 ci x 64 l
    const int dm = idx >> 4, dk = idx & 15;   // Ds stage: 64 o x 16 ci
    for (int c0 = 0; c0 < CIN; c0 += 16) {
      float4 vx = *(const float4*)(xb + (size_t)(c0 + xk) * LEN + l0 + xl);
      *(float4*)&As[xk][xl] = vx;
      float4 vd = *(const float4*)(dw + (size_t)(o0 + dm) * CIN + c0 + dk);
      Bs[dk + 0][dm] = vd.x; Bs[dk + 1][dm] = vd.y; Bs[dk + 2][dm] = vd.z; Bs[dk + 3][dm] = vd.w;
      __syncthreads();
#pragma unroll
      for (int kk = 0; kk < 16; ++kk) {
        const float4 a  = *(const float4*)&Bs[kk][ty * 4];   // o
        const float4 bb = *(const float4*)&As[kk][tx * 4];   // l
        const float av[4] = {a.x, a.y, a.z, a.w};
        const float bv[4] = {bb.x, bb.y, bb.z, bb.w};
#pragma unroll
        for (int i = 0; i < 4; ++i)
#pragma unroll
          for (int j = 0; j < 4; ++j) acc2[i][j] += av[i] * bv[j];
      }
      __syncthreads();
    }
  }

#pragma unroll
  for (int i = 0; i < 4; ++i) {
    const int o = o0 + ty * 4 + i;
    const float dbv = db[o];
    float vals[4];
#pragma unroll
    for (int j = 0; j < 4; ++j) {
      float vv = r1[i][j] + acc2[i][j] + dbv;
      vals[j] = vv > 0.f ? vv : 0.f;
    }
    *(float4*)(out + ((size_t)b * COUT + o) * LEN + l0 + tx * 4) =
        make_float4(vals[0], vals[1], vals[2], vals[3]);
  }
}

// ---------------------------------------------------------------------------
extern "C" void kernel_launch(void* const* d_in, const int* in_sizes, int n_in,
                              void* d_out, int out_size, void* d_ws, size_t ws_size,
                              hipStream_t stream)
{
  (void)in_sizes; (void)n_in; (void)out_size; (void)ws_size;
  const float* x   = (const float*)d_in[0];
  const float* c1v = (const float*)d_in[1];
  const float* c1g = (const float*)d_in[2];
  const float* c1b = (const float*)d_in[3];
  const float* qw  = (const float*)d_in[4];
  const float* qb  = (const float*)d_in[5];
  const float* rpb = (const float*)d_in[6];
  const float* pw  = (const float*)d_in[7];
  const float* pb  = (const float*)d_in[8];
  const float* dw  = (const float*)d_in[9];
  const float* db  = (const float*)d_in[10];
  float* out = (float*)d_out;

  char* ws = (char*)d_ws;
  float* w1  = (float*)(ws);                                    //   917,504 B
  float* h   = (float*)(ws + (1u << 20));                       //  33,652,736 B (B,L2V,COUT)
  float* qkv = (float*)(ws + (1u << 20) + 33652736u);           // 100,958,208 B (B*L2V, 768)
  float* ao  = h;  // reuse h region after qkv GEMM has consumed h

  wn_kernel<<<COUT, 256, 0, stream>>>(c1v, c1g, w1);
  zero_hpad_kernel<<<(BATCH * PADW * COUT) / 256, 256, 0, stream>>>(h);
  conv_kernel<<<dim3(LEN / 64, COUT / 64, BATCH), 256, 0, stream>>>(x, w1, c1b, h);
  const int M = BATCH * L2V;  // 32864
  gemm_bias_kernel<<<dim3((M + 63) / 64, NQKV / 64), 256, 0, stream>>>(h, qw, qb, qkv, M, NQKV, COUT);
  attn_kernel<<<(BATCH * LEN) / 4, 256, 0, stream>>>(qkv, rpb, ao);
  proj_res_kernel<<<dim3(LEN / 64, COUT / 64, BATCH), 256, 0, stream>>>(ao, pw, pb, x, dw, db, out);
}

// Round 2
// 127.868 us; speedup vs baseline: 4.4943x; 4.4943x over previous
//
#include <hip/hip_runtime.h>
#include <math.h>

#define KW 7
#define PADW 12
#define BATCH 8
#define CIN 128
#define COUT 256
#define LEN 4096
#define L2V 4108
#define NQKV 768
#define MROWS (BATCH * L2V)   // 32864

typedef unsigned short u16;
typedef short v8s __attribute__((ext_vector_type(8)));
typedef float v4f __attribute__((ext_vector_type(4)));

__device__ __forceinline__ u16 f2bf(float f) {
  unsigned int x = __float_as_uint(f);
  x += 0x7fffu + ((x >> 16) & 1u);
  return (u16)(x >> 16);
}
__device__ __forceinline__ float bf2f(u16 u) {
  return __uint_as_float(((unsigned int)u) << 16);
}

// ---------------------------------------------------------------------------
// prep 1: weight norm -> wt[t][c][ci] bf16
// ---------------------------------------------------------------------------
__global__ __launch_bounds__(256) void prep_wn(
    const float* __restrict__ v, const float* __restrict__ g,
    u16* __restrict__ wt)
{
  const int c = blockIdx.x;
  const float* vo = v + (size_t)c * (CIN * KW);
  float s = 0.f;
  for (int i = threadIdx.x; i < CIN * KW; i += 256) { float t = vo[i]; s += t * t; }
#pragma unroll
  for (int off = 1; off < 64; off <<= 1) s += __shfl_xor(s, off);
  __shared__ float red[4];
  if ((threadIdx.x & 63) == 0) red[threadIdx.x >> 6] = s;
  __syncthreads();
  const float tot = red[0] + red[1] + red[2] + red[3];
  const float scale = g[c] / sqrtf(tot);
  for (int i = threadIdx.x; i < CIN * KW; i += 256) {
    const int ci = i / 7, t = i - ci * 7;
    wt[((size_t)t * COUT + c) * CIN + ci] = f2bf(vo[i] * scale);
  }
}

// ---------------------------------------------------------------------------
// prep 2: cast qw/pw/dw to bf16 (same row-major layouts)
// ---------------------------------------------------------------------------
__global__ __launch_bounds__(256) void prep_cast(
    const float* __restrict__ qw, const float* __restrict__ pw,
    const float* __restrict__ dw, u16* __restrict__ qwb,
    u16* __restrict__ pwb, u16* __restrict__ dwb)
{
  const int i4 = (blockIdx.x * 256 + threadIdx.x) * 4;
  const float* src; u16* dst; int off;
  if (i4 < 196608)      { src = qw; dst = qwb; off = i4; }
  else if (i4 < 262144) { src = pw; dst = pwb; off = i4 - 196608; }
  else                  { src = dw; dst = dwb; off = i4 - 262144; }
  const float4 vv = *(const float4*)(src + off);
  *(ushort4*)(dst + off) = make_ushort4(f2bf(vv.x), f2bf(vv.y), f2bf(vv.z), f2bf(vv.w));
}

// ---------------------------------------------------------------------------
// prep 3: zero pad rows of h and xT
// ---------------------------------------------------------------------------
__global__ __launch_bounds__(256) void zero_pads(u16* __restrict__ h, u16* __restrict__ xT)
{
  const int idx = blockIdx.x * 256 + threadIdx.x;   // < 36864
  if (idx < 24576) {
    const int b = idx / 3072, r = idx - b * 3072;
    h[(size_t)b * L2V * COUT + r] = 0;
  } else {
    const int k = idx - 24576;
    const int b = k / 1536, r = k - b * 1536;
    xT[(size_t)b * L2V * CIN + r] = 0;
  }
}

// ---------------------------------------------------------------------------
// prep 4: transpose x[b][ci][p] f32 -> xT[b][12+p][ci] bf16
// ---------------------------------------------------------------------------
__global__ __launch_bounds__(256) void xpose(const float* __restrict__ x, u16* __restrict__ xT)
{
  const int b = blockIdx.y, p0 = blockIdx.x * 64;
  const int tx = threadIdx.x & 15, ty = threadIdx.x >> 4;
  const int p = p0 + ty * 4;
  const float* xb = x + (size_t)b * CIN * LEN;
  u16* xTb = xT + (size_t)b * L2V * CIN + (size_t)(PADW + p) * CIN;
#pragma unroll
  for (int half = 0; half < 2; ++half) {
    const int ci0 = half * 64 + tx * 4;
    float r[4][4];
#pragma unroll
    for (int i = 0; i < 4; ++i)
      *(float4*)r[i] = *(const float4*)(xb + (size_t)(ci0 + i) * LEN + p);
#pragma unroll
    for (int j = 0; j < 4; ++j)
      *(ushort4*)(xTb + (size_t)j * CIN + ci0) =
          make_ushort4(f2bf(r[0][j]), f2bf(r[1][j]), f2bf(r[2][j]), f2bf(r[3][j]));
  }
}

// ---------------------------------------------------------------------------
// Kernel: conv via MFMA.  C[c][p] = sum_{t,ci} wt[t][c][ci] * xT[p+2t][ci]
// 128(c) x 128(p) tile, 4 waves, K-step 32, 7*4 = 28 steps.
// ---------------------------------------------------------------------------
__global__ __launch_bounds__(256) void conv_mfma(
    const u16* __restrict__ wt, const u16* __restrict__ xT,
    const float* __restrict__ bias, u16* __restrict__ h)
{
  const int b = blockIdx.z;
  const int c0 = blockIdx.y * 128;
  const int p0 = blockIdx.x * 128;
  const int tid = threadIdx.x;
  const int lane = tid & 63;
  const int w = tid >> 6;
  const int wr = w >> 1, wc = w & 1;

  __shared__ u16 As[128 * 32];
  __shared__ u16 Bs[128 * 32];

  v4f acc[4][4];
#pragma unroll
  for (int i = 0; i < 4; ++i)
#pragma unroll
    for (int j = 0; j < 4; ++j) acc[i][j] = (v4f){0.f, 0.f, 0.f, 0.f};

  const int row0 = tid >> 2;
  const int ch0 = tid & 3;
  const int swz = (ch0 ^ ((row0 >> 1) & 3)) * 8;
  const size_t xTb = (size_t)b * L2V * CIN;

  int4 ra0, ra1, rb0, rb1;
  auto do_load = [&](int step) {
    const int t = step >> 2, ci0 = (step & 3) << 5;
    const u16* Ap = wt + ((size_t)(t * COUT + c0 + row0) * CIN + ci0 + swz);
    ra0 = *(const int4*)Ap;
    ra1 = *(const int4*)(Ap + 64 * CIN);
    const u16* Bp = xT + (xTb + (size_t)(p0 + 2 * t + row0) * CIN + ci0 + swz);
    rb0 = *(const int4*)Bp;
    rb1 = *(const int4*)(Bp + 64 * CIN);
  };

  const int rdA = (wr * 64 + (lane & 15)) * 32;
  const int rdB = (wc * 64 + (lane & 15)) * 32;
  const int ksw = (((lane >> 4) ^ (((lane & 15) >> 1) & 3)) * 8);

  do_load(0);
  for (int step = 0; step < 28; ++step) {
    __syncthreads();
    *(int4*)&As[tid * 8] = ra0;
    *(int4*)&As[tid * 8 + 2048] = ra1;
    *(int4*)&Bs[tid * 8] = rb0;
    *(int4*)&Bs[tid * 8 + 2048] = rb1;
    if (step < 27) do_load(step + 1);
    __syncthreads();
    v8s a[4], bb[4];
#pragma unroll
    for (int f = 0; f < 4; ++f) a[f] = *(const v8s*)&As[rdA + f * 512 + ksw];
#pragma unroll
    for (int f = 0; f < 4; ++f) bb[f] = *(const v8s*)&Bs[rdB + f * 512 + ksw];
#pragma unroll
    for (int fi = 0; fi < 4; ++fi)
#pragma unroll
      for (int fj = 0; fj < 4; ++fj)
        acc[fi][fj] = __builtin_amdgcn_mfma_f32_16x16x32_bf16(a[fi], bb[fj], acc[fi][fj], 0, 0, 0);
  }

  const int subl = lane >> 4;
#pragma unroll
  for (int fi = 0; fi < 4; ++fi) {
    const int cb = c0 + wr * 64 + fi * 16 + subl * 4;
    const float4 bv = *(const float4*)(bias + cb);
#pragma unroll
    for (int fj = 0; fj < 4; ++fj) {
      const int p = p0 + wc * 64 + fj * 16 + (lane & 15);
      float v0 = acc[fi][fj][0] + bv.x; v0 = v0 > 0.f ? v0 : 0.f;
      float v1 = acc[fi][fj][1] + bv.y; v1 = v1 > 0.f ? v1 : 0.f;
      float v2 = acc[fi][fj][2] + bv.z; v2 = v2 > 0.f ? v2 : 0.f;
      float v3 = acc[fi][fj][3] + bv.w; v3 = v3 > 0.f ? v3 : 0.f;
      *(ushort4*)(h + ((size_t)b * L2V + PADW + p) * COUT + cb) =
          make_ushort4(f2bf(v0), f2bf(v1), f2bf(v2), f2bf(v3));
    }
  }
}

// ---------------------------------------------------------------------------
// Kernel: qkv GEMM.  C[n][m] = sum_k qwb[n][k] * h[m][k] + qb[n]
// n over 768 (6 tiles), m over 32864 (257 tiles, edge clamped/guarded)
// ---------------------------------------------------------------------------
__global__ __launch_bounds__(256) void qkv_mfma(
    const u16* __restrict__ qwb, const u16* __restrict__ h,
    const float* __restrict__ qb, u16* __restrict__ qkv)
{
  const int m0 = blockIdx.x * 128;
  const int n0 = blockIdx.y * 128;
  const int tid = threadIdx.x;
  const int lane = tid & 63;
  const int w = tid >> 6;
  const int wr = w >> 1, wc = w & 1;

  __shared__ u16 As[128 * 32];
  __shared__ u16 Bs[128 * 32];

  v4f acc[4][4];
#pragma unroll
  for (int i = 0; i < 4; ++i)
#pragma unroll
    for (int j = 0; j < 4; ++j) acc[i][j] = (v4f){0.f, 0.f, 0.f, 0.f};

  const int row0 = tid >> 2;
  const int ch0 = tid & 3;
  const int swz = (ch0 ^ ((row0 >> 1) & 3)) * 8;
  const int mr0 = min(m0 + row0, MROWS - 1);
  const int mr1 = min(m0 + row0 + 64, MROWS - 1);

  int4 ra0, ra1, rb0, rb1;
  auto do_load = [&](int step) {
    const int k0 = step << 5;
    const u16* Ap = qwb + ((size_t)(n0 + row0) * COUT + k0 + swz);
    ra0 = *(const int4*)Ap;
    ra1 = *(const int4*)(Ap + 64 * COUT);
    rb0 = *(const int4*)(h + ((size_t)mr0 * COUT + k0 + swz));
    rb1 = *(const int4*)(h + ((size_t)mr1 * COUT + k0 + swz));
  };

  const int rdA = (wr * 64 + (lane & 15)) * 32;
  const int rdB = (wc * 64 + (lane & 15)) * 32;
  const int ksw = (((lane >> 4) ^ (((lane & 15) >> 1) & 3)) * 8);

  do_load(0);
  for (int step = 0; step < 8; ++step) {
    __syncthreads();
    *(int4*)&As[tid * 8] = ra0;
    *(int4*)&As[tid * 8 + 2048] = ra1;
    *(int4*)&Bs[tid * 8] = rb0;
    *(int4*)&Bs[tid * 8 + 2048] = rb1;
    if (step < 7) do_load(step + 1);
    __syncthreads();
    v8s a[4], bb[4];
#pragma unroll
    for (int f = 0; f < 4; ++f) a[f] = *(const v8s*)&As[rdA + f * 512 + ksw];
#pragma unroll
    for (int f = 0; f < 4; ++f) bb[f] = *(const v8s*)&Bs[rdB + f * 512 + ksw];
#pragma unroll
    for (int fi = 0; fi < 4; ++fi)
#pragma unroll
      for (int fj = 0; fj < 4; ++fj)
        acc[fi][fj] = __builtin_amdgcn_mfma_f32_16x16x32_bf16(a[fi], bb[fj], acc[fi][fj], 0, 0, 0);
  }

  const int subl = lane >> 4;
#pragma unroll
  for (int fi = 0; fi < 4; ++fi) {
    const int nb = n0 + wr * 64 + fi * 16 + subl * 4;
    const float4 bv = *(const float4*)(qb + nb);
#pragma unroll
    for (int fj = 0; fj < 4; ++fj) {
      const int m = m0 + wc * 64 + fj * 16 + (lane & 15);
      if (m < MROWS) {
        *(ushort4*)(qkv + (size_t)m * NQKV + nb) =
            make_ushort4(f2bf(acc[fi][fj][0] + bv.x), f2bf(acc[fi][fj][1] + bv.y),
                         f2bf(acc[fi][fj][2] + bv.z), f2bf(acc[fi][fj][3] + bv.w));
      }
    }
  }
}

// ---------------------------------------------------------------------------
// Kernel: NATTEN attention on bf16 qkv. One wave per (b,j); lane owns 4 ch.
// ---------------------------------------------------------------------------
__global__ __launch_bounds__(256) void attn_bf16(
    const u16* __restrict__ qkv, const float* __restrict__ rpb,
    u16* __restrict__ ao)
{
  const int wid = (blockIdx.x << 2) + (threadIdx.x >> 6);
  const int lane = threadIdx.x & 63;
  const int b = wid >> 12;
  const int j = wid & 4095;
  const int r = j & 1, ii = j >> 1;
  int start = ii - 3;
  start = start < 0 ? 0 : start;
  start = start > 2047 ? 2047 : start;

  const u16* base = qkv + (size_t)b * L2V * NQKV;
  const ushort4 qv = *(const ushort4*)(base + (size_t)j * NQKV + 4 * lane);
  const float q0 = bf2f(qv.x) * 0.0625f, q1 = bf2f(qv.y) * 0.0625f;
  const float q2 = bf2f(qv.z) * 0.0625f, q3 = bf2f(qv.w) * 0.0625f;

  float sc[7];
  float mx = -1e30f;
#pragma unroll
  for (int t = 0; t < 7; ++t) {
    const int pos = r + 2 * (start + t);
    const ushort4 kv = *(const ushort4*)(base + (size_t)pos * NQKV + COUT + 4 * lane);
    float s = q0 * bf2f(kv.x) + q1 * bf2f(kv.y) + q2 * bf2f(kv.z) + q3 * bf2f(kv.w);
#pragma unroll
    for (int o = 1; o < 64; o <<= 1) s += __shfl_xor(s, o);
    s += rpb[start + t - ii + 6];
    sc[t] = s;
    mx = fmaxf(mx, s);
  }
  float sum = 0.f;
#pragma unroll
  for (int t = 0; t < 7; ++t) { sc[t] = __expf(sc[t] - mx); sum += sc[t]; }
  const float inv = 1.f / sum;

  float a0 = 0.f, a1 = 0.f, a2 = 0.f, a3 = 0.f;
#pragma unroll
  for (int t = 0; t < 7; ++t) {
    const int pos = r + 2 * (start + t);
    const ushort4 vv = *(const ushort4*)(base + (size_t)pos * NQKV + 2 * COUT + 4 * lane);
    const float wgt = sc[t] * inv;
    a0 += wgt * bf2f(vv.x); a1 += wgt * bf2f(vv.y);
    a2 += wgt * bf2f(vv.z); a3 += wgt * bf2f(vv.w);
  }
  *(ushort4*)(ao + ((size_t)(b * LEN + j)) * COUT + 4 * lane) =
      make_ushort4(f2bf(a0), f2bf(a1), f2bf(a2), f2bf(a3));
}

// ---------------------------------------------------------------------------
// Kernel: fused proj + ds residual + double relu.
// C[l][o] = relu( relu(sum_c ao[l][c] pwb[o][c] + pb[o]) +
//                 sum_ci xT[12+l][ci] dwb[o][ci] + db[o] ) -> out[b][o][l] f32
// ---------------------------------------------------------------------------
__global__ __launch_bounds__(256) void projds_mfma(
    const u16* __restrict__ ao, const u16* __restrict__ pwb,
    const float* __restrict__ pb, const u16* __restrict__ xT,
    const u16* __restrict__ dwb, const float* __restrict__ db,
    float* __restrict__ out)
{
  const int b = blockIdx.z;
  const int l0 = blockIdx.x * 128;
  const int o0 = blockIdx.y * 128;
  const int tid = threadIdx.x;
  const int lane = tid & 63;
  const int w = tid >> 6;
  const int wr = w >> 1, wc = w & 1;

  __shared__ u16 As[128 * 32];
  __shared__ u16 Bs[128 * 32];

  v4f acc[4][4];
#pragma unroll
  for (int i = 0; i < 4; ++i)
#pragma unroll
    for (int j = 0; j < 4; ++j) acc[i][j] = (v4f){0.f, 0.f, 0.f, 0.f};

  const int row0 = tid >> 2;
  const int ch0 = tid & 3;
  const int swz = (ch0 ^ ((row0 >> 1) & 3)) * 8;

  int4 ra0, ra1, rb0, rb1;
  auto load1 = [&](int step) {   // A = ao rows l, B = pwb rows o, K=256
    const int k0 = step << 5;
    const u16* Ap = ao + ((size_t)(b * LEN + l0 + row0) * COUT + k0 + swz);
    ra0 = *(const int4*)Ap;
    ra1 = *(const int4*)(Ap + 64 * COUT);
    const u16* Bp = pwb + ((size_t)(o0 + row0) * COUT + k0 + swz);
    rb0 = *(const int4*)Bp;
    rb1 = *(const int4*)(Bp + 64 * COUT);
  };
  auto load2 = [&](int step) {   // A = xT rows 12+l, B = dwb rows o, K=128
    const int k0 = step << 5;
    const u16* Ap = xT + ((size_t)b * L2V + PADW + l0 + row0) * CIN + k0 + swz;
    ra0 = *(const int4*)Ap;
    ra1 = *(const int4*)(Ap + 64 * CIN);
    const u16* Bp = dwb + ((size_t)(o0 + row0) * CIN + k0 + swz);
    rb0 = *(const int4*)Bp;
    rb1 = *(const int4*)(Bp + 64 * CIN);
  };

  const int rdA = (wr * 64 + (lane & 15)) * 32;
  const int rdB = (wc * 64 + (lane & 15)) * 32;
  const int ksw = (((lane >> 4) ^ (((lane & 15) >> 1) & 3)) * 8);

  load1(0);
  for (int step = 0; step < 8; ++step) {
    __syncthreads();
    *(int4*)&As[tid * 8] = ra0;
    *(int4*)&As[tid * 8 + 2048] = ra1;
    *(int4*)&Bs[tid * 8] = rb0;
    *(int4*)&Bs[tid * 8 + 2048] = rb1;
    if (step < 7) load1(step + 1); else load2(0);
    __syncthreads();
    v8s a[4], bb[4];
#pragma unroll
    for (int f = 0; f < 4; ++f) a[f] = *(const v8s*)&As[rdA + f * 512 + ksw];
#pragma unroll
    for (int f = 0; f < 4; ++f) bb[f] = *(const v8s*)&Bs[rdB + f * 512 + ksw];
#pragma unroll
    for (int fi = 0; fi < 4; ++fi)
#pragma unroll
      for (int fj = 0; fj < 4; ++fj)
        acc[fi][fj] = __builtin_amdgcn_mfma_f32_16x16x32_bf16(a[fi], bb[fj], acc[fi][fj], 0, 0, 0);
  }

  // boundary: acc = relu(acc + pb[o]), then phase-2 accumulates on top
#pragma unroll
  for (int fj = 0; fj < 4; ++fj) {
    const int o = o0 + wc * 64 + fj * 16 + (lane & 15);
    const float pbv = pb[o];
#pragma unroll
    for (int fi = 0; fi < 4; ++fi)
#pragma unroll
      for (int jj = 0; jj < 4; ++jj) {
        float vv = acc[fi][fj][jj] + pbv;
        acc[fi][fj][jj] = vv > 0.f ? vv : 0.f;
      }
  }

  for (int step = 0; step < 4; ++step) {
    __syncthreads();
    *(int4*)&As[tid * 8] = ra0;
    *(int4*)&As[tid * 8 + 2048] = ra1;
    *(int4*)&Bs[tid * 8] = rb0;
    *(int4*)&Bs[tid * 8 + 2048] = rb1;
    if (step < 3) load2(step + 1);
    __syncthreads();
    v8s a[4], bb[4];
#pragma unroll
    for (int f = 0; f < 4; ++f) a[f] = *(const v8s*)&As[rdA + f * 512 + ksw];
#pragma unroll
    for (int f = 0; f < 4; ++f) bb[f] = *(const v8s*)&Bs[rdB + f * 512 + ksw];
#pragma unroll
    for (int fi = 0; fi < 4; ++fi)
#pragma unroll
      for (int fj = 0; fj < 4; ++fj)
        acc[fi][fj] = __builtin_amdgcn_mfma_f32_16x16x32_bf16(a[fi], bb[fj], acc[fi][fj], 0, 0, 0);
  }

  const int subl = lane >> 4;
#pragma unroll
  for (int fj = 0; fj < 4; ++fj) {
    const int o = o0 + wc * 64 + fj * 16 + (lane & 15);
    const float dbv = db[o];
    float* orow = out + ((size_t)(b * COUT + o)) * LEN;
#pragma unroll
    for (int fi = 0; fi < 4; ++fi) {
      const int lb = l0 + wr * 64 + fi * 16 + subl * 4;
      float v0 = acc[fi][fj][0] + dbv; v0 = v0 > 0.f ? v0 : 0.f;
      float v1 = acc[fi][fj][1] + dbv; v1 = v1 > 0.f ? v1 : 0.f;
      float v2 = acc[fi][fj][2] + dbv; v2 = v2 > 0.f ? v2 : 0.f;
      float v3 = acc[fi][fj][3] + dbv; v3 = v3 > 0.f ? v3 : 0.f;
      *(float4*)(orow + lb) = make_float4(v0, v1, v2, v3);
    }
  }
}

// ---------------------------------------------------------------------------
extern "C" void kernel_launch(void* const* d_in, const int* in_sizes, int n_in,
                              void* d_out, int out_size, void* d_ws, size_t ws_size,
                              hipStream_t stream)
{
  (void)in_sizes; (void)n_in; (void)out_size; (void)ws_size;
  const float* x   = (const float*)d_in[0];
  const float* c1v = (const float*)d_in[1];
  const float* c1g = (const float*)d_in[2];
  const float* c1b = (const float*)d_in[3];
  const float* qw  = (const float*)d_in[4];
  const float* qb  = (const float*)d_in[5];
  const float* rpb = (const float*)d_in[6];
  const float* pw  = (const float*)d_in[7];
  const float* pb  = (const float*)d_in[8];
  const float* dw  = (const float*)d_in[9];
  const float* db  = (const float*)d_in[10];
  float* out = (float*)d_out;

  char* ws = (char*)d_ws;
  u16* wt  = (u16*)(ws);                       // 458,752 B
  u16* qwb = (u16*)(ws + 458752);              // 393,216 B
  u16* pwb = (u16*)(ws + 851968);              // 131,072 B
  u16* dwb = (u16*)(ws + 983040);              //  65,536 B
  u16* xT  = (u16*)(ws + 1048576);             // 8,413,184 B
  u16* h   = (u16*)(ws + 9461760);             // 16,826,368 B
  u16* qkv = (u16*)(ws + 26288128);            // 50,479,104 B
  u16* ao  = (u16*)(ws + 76767232);            // 16,777,216 B  (end ~93.5 MB)

  prep_wn<<<COUT, 256, 0, stream>>>(c1v, c1g, wt);
  prep_cast<<<288, 256, 0, stream>>>(qw, pw, dw, qwb, pwb, dwb);
  zero_pads<<<144, 256, 0, stream>>>(h, xT);
  xpose<<<dim3(LEN / 64, BATCH), 256, 0, stream>>>(x, xT);
  conv_mfma<<<dim3(LEN / 128, COUT / 128, BATCH), 256, 0, stream>>>(wt, xT, c1b, h);
  qkv_mfma<<<dim3((MROWS + 127) / 128, NQKV / 128), 256, 0, stream>>>(qwb, h, qb, qkv);
  attn_bf16<<<(BATCH * LEN) / 4, 256, 0, stream>>>(qkv, rpb, ao);
  projds_mfma<<<dim3(LEN / 128, COUT / 128, BATCH), 256, 0, stream>>>(ao, pwb, pb, xT, dwb, db, out);
}